// Round 9
// baseline (35.498 us; speedup 1.0000x reference)
//
#include <hip/hip_runtime.h>

#define TILE    16
#define BLOCK   256
#define EMBED   128
#define VOCAB   50257
#define ESTRIDE 132   // 4*odd floats: spreads rows across bank-groups
#define NPART   2048

// ---------- pre-pass: fc fp32 -> bf16 (round-to-nearest-even) into d_ws ----
__global__ __launch_bounds__(256) void hs_pack(
    const float* __restrict__ fc, ushort* __restrict__ out, int n)
{
    const int stride = gridDim.x * 256 * 8;
    for (int i = (blockIdx.x * 256 + threadIdx.x) * 8; i < n; i += stride) {
        const uint4 a = *(const uint4*)(fc + i);
        const uint4 b = *(const uint4*)(fc + i + 4);
        ushort r[8];
        const uint* u = &a.x;
        #pragma unroll
        for (int j = 0; j < 4; ++j)
            r[j] = (ushort)((u[j] + 0x7FFFu + ((u[j] >> 16) & 1u)) >> 16);
        const uint* v = &b.x;
        #pragma unroll
        for (int j = 0; j < 4; ++j)
            r[4 + j] = (ushort)((v[j] + 0x7FFFu + ((v[j] >> 16) & 1u)) >> 16);
        *(uint4*)(out + i) = *(uint4*)r;
    }
}

// ---------- main: R5 skeleton, fc gathered as bf16 (256B rows, 4 lines) ----
// 4-lane quad per (token, path-node) item; quad's 4 lanes read adjacent 16B
// chunks of the 256B bf16 row -> whole 64B lines, 4 loads/lane-item.
__global__ __launch_bounds__(BLOCK) void hs_main_bf16(
    const float* __restrict__ emb,        // [T, 128]
    const int*   __restrict__ target,     // [T]
    const ushort* __restrict__ fcb,       // [V-1, 128] bf16
    const int*   __restrict__ path_idx,   // [V, D]
    const float* __restrict__ path_code,  // [V, D]
    const float* __restrict__ path_mask,  // [V, D]
    int T, int D,
    float* __restrict__ partial_b,
    float* __restrict__ partial_c)
{
    extern __shared__ char smem[];
    float* se  = (float*)smem;                          // [TILE*ESTRIDE]
    int2*  sic = (int2*)(smem + TILE * ESTRIDE * 4);    // [TILE*D], d-major
    __shared__ float sb[BLOCK / 64];
    __shared__ float sc[BLOCK / 64];

    const int tok0 = blockIdx.x * TILE;
    const int ntok = min(TILE, T - tok0);

    const float4* g4 = (const float4*)(emb + (size_t)tok0 * EMBED);
    for (int j = threadIdx.x; j < TILE * (EMBED / 4); j += BLOCK) {
        const int f = j * 4, tk = f >> 7, kk = f & 127;
        float4 v = make_float4(0.f, 0.f, 0.f, 0.f);
        if (tk < ntok) v = g4[j];
        *(float4*)&se[tk * ESTRIDE + kk] = v;
    }
    for (int j = threadIdx.x; j < TILE * D; j += BLOCK) {
        const int tk = j & (TILE - 1), d = j >> 4;
        int2 m = make_int2(0, __float_as_int(-1.0f));
        if (tk < ntok) {
            const int v = target[tok0 + tk];
            const size_t po = (size_t)v * D + d;
            if (path_mask[po] != 0.f)
                m = make_int2(path_idx[po], __float_as_int(path_code[po]));
        }
        sic[j] = m;
    }
    __syncthreads();

    const int wave = threadIdx.x >> 6;
    const int g    = (threadIdx.x >> 2) & 15;   // quad id = token tk
    const int sub  = threadIdx.x & 3;

    float accb = 0.f, accc = 0.f;

    const int items = TILE * D;
    for (int it = wave * 16; it < items; it += 64) {
        const int item = it + g;                // d = it>>4 (wave-uniform)
        const int2 m = sic[item];
        const float code = __int_as_float(m.y);
        if (code >= 0.f) {
            const char*   wrow = (const char*)(fcb + (size_t)m.x * EMBED);
            const float4* e4   = (const float4*)&se[g * ESTRIDE];
            float s0 = 0.f, s1 = 0.f;
            #pragma unroll
            for (int k = 0; k < 4; ++k) {
                const int c8 = k * 4 + sub;              // 16B chunk id 0..15
                const uint4  wv = *(const uint4*)(wrow + (c8 << 4));
                const float4 ea = e4[c8 * 2];
                const float4 eb = e4[c8 * 2 + 1];
                s0 = fmaf(ea.x, __uint_as_float(wv.x << 16),        s0);
                s1 = fmaf(ea.y, __uint_as_float(wv.x & 0xFFFF0000u), s1);
                s0 = fmaf(ea.z, __uint_as_float(wv.y << 16),        s0);
                s1 = fmaf(ea.w, __uint_as_float(wv.y & 0xFFFF0000u), s1);
                s0 = fmaf(eb.x, __uint_as_float(wv.z << 16),        s0);
                s1 = fmaf(eb.y, __uint_as_float(wv.z & 0xFFFF0000u), s1);
                s0 = fmaf(eb.z, __uint_as_float(wv.w << 16),        s0);
                s1 = fmaf(eb.w, __uint_as_float(wv.w & 0xFFFF0000u), s1);
            }
            float x = s0 + s1;
            x += __shfl_xor(x, 1);
            x += __shfl_xor(x, 2);
            accb += fmaxf(x, 0.f) - x * code + __logf(1.f + __expf(-fabsf(x)));
            accc += 1.f;                        // 4x overcount cancels
        }
    }

    #pragma unroll
    for (int o = 32; o > 0; o >>= 1) {
        accb += __shfl_xor(accb, o);
        accc += __shfl_xor(accc, o);
    }
    const int lane = threadIdx.x & 63;
    if (lane == 0) { sb[wave] = accb; sc[wave] = accc; }
    __syncthreads();
    if (threadIdx.x == 0) {
        float b = 0.f, c = 0.f;
        #pragma unroll
        for (int i = 0; i < BLOCK / 64; ++i) { b += sb[i]; c += sc[i]; }
        partial_b[blockIdx.x] = b;
        partial_c[blockIdx.x] = c;
    }
}

// ---------- fp32 fallback (R5 kernel) if ws is too small ----------
__global__ __launch_bounds__(BLOCK) void hs_main_f32(
    const float* __restrict__ emb, const int* __restrict__ target,
    const float* __restrict__ fc,  const int* __restrict__ path_idx,
    const float* __restrict__ path_code, const float* __restrict__ path_mask,
    int T, int D, float* __restrict__ partial_b, float* __restrict__ partial_c)
{
    extern __shared__ char smem[];
    float* se  = (float*)smem;
    int2*  sic = (int2*)(smem + TILE * ESTRIDE * 4);
    __shared__ float sb[BLOCK / 64];
    __shared__ float sc[BLOCK / 64];

    const int tok0 = blockIdx.x * TILE;
    const int ntok = min(TILE, T - tok0);

    const float4* g4 = (const float4*)(emb + (size_t)tok0 * EMBED);
    for (int j = threadIdx.x; j < TILE * (EMBED / 4); j += BLOCK) {
        const int f = j * 4, tk = f >> 7, kk = f & 127;
        float4 v = make_float4(0.f, 0.f, 0.f, 0.f);
        if (tk < ntok) v = g4[j];
        *(float4*)&se[tk * ESTRIDE + kk] = v;
    }
    for (int j = threadIdx.x; j < TILE * D; j += BLOCK) {
        const int tk = j & (TILE - 1), d = j >> 4;
        int2 m = make_int2(0, __float_as_int(-1.0f));
        if (tk < ntok) {
            const int v = target[tok0 + tk];
            const size_t po = (size_t)v * D + d;
            if (path_mask[po] != 0.f)
                m = make_int2(path_idx[po], __float_as_int(path_code[po]));
        }
        sic[j] = m;
    }
    __syncthreads();

    const int wave = threadIdx.x >> 6;
    const int g    = (threadIdx.x >> 2) & 15;
    const int sub  = threadIdx.x & 3;
    float accb = 0.f, accc = 0.f;

    const int items = TILE * D;
    for (int it = wave * 16; it < items; it += 64) {
        const int item = it + g;
        const int2 m = sic[item];
        const float code = __int_as_float(m.y);
        if (code >= 0.f) {
            const float4* w4 = (const float4*)(fc + (size_t)m.x * EMBED);
            const float4* e4 = (const float4*)&se[g * ESTRIDE];
            float s0 = 0.f, s1 = 0.f, s2 = 0.f, s3 = 0.f;
            #pragma unroll
            for (int k = 0; k < 8; ++k) {
                const float4 w  = w4[k * 4 + sub];
                const float4 ev = e4[k * 4 + sub];
                s0 = fmaf(ev.x, w.x, s0); s1 = fmaf(ev.y, w.y, s1);
                s2 = fmaf(ev.z, w.z, s2); s3 = fmaf(ev.w, w.w, s3);
            }
            float x = (s0 + s1) + (s2 + s3);
            x += __shfl_xor(x, 1); x += __shfl_xor(x, 2);
            accb += fmaxf(x, 0.f) - x * code + __logf(1.f + __expf(-fabsf(x)));
            accc += 1.f;
        }
    }
    #pragma unroll
    for (int o = 32; o > 0; o >>= 1) {
        accb += __shfl_xor(accb, o);
        accc += __shfl_xor(accc, o);
    }
    const int lane = threadIdx.x & 63;
    if (lane == 0) { sb[wave] = accb; sc[wave] = accc; }
    __syncthreads();
    if (threadIdx.x == 0) {
        float b = 0.f, c = 0.f;
        #pragma unroll
        for (int i = 0; i < BLOCK / 64; ++i) { b += sb[i]; c += sc[i]; }
        partial_b[blockIdx.x] = b;
        partial_c[blockIdx.x] = c;
    }
}

// ---------- deterministic finalize ----------
__global__ __launch_bounds__(256) void hs_finalize(
    const float* __restrict__ pb, const float* __restrict__ pc,
    int n, float* __restrict__ out)
{
    __shared__ double rb[256];
    __shared__ double rc[256];
    double sbv = 0.0, scv = 0.0;
    for (int i = threadIdx.x; i < n; i += 256) {
        sbv += (double)pb[i];
        scv += (double)pc[i];
    }
    rb[threadIdx.x] = sbv; rc[threadIdx.x] = scv;
    __syncthreads();
    for (int s = 128; s > 0; s >>= 1) {
        if (threadIdx.x < s) {
            rb[threadIdx.x] += rb[threadIdx.x + s];
            rc[threadIdx.x] += rc[threadIdx.x + s];
        }
        __syncthreads();
    }
    if (threadIdx.x == 0) out[0] = (float)(rb[0] / rc[0]);
}

extern "C" void kernel_launch(void* const* d_in, const int* in_sizes, int n_in,
                              void* d_out, int out_size, void* d_ws, size_t ws_size,
                              hipStream_t stream) {
    const float* emb   = (const float*)d_in[0];
    const int*   tgt   = (const int*)  d_in[1];
    const float* fc    = (const float*)d_in[2];
    const int*   pidx  = (const int*)  d_in[3];
    const float* pcode = (const float*)d_in[4];
    const float* pmask = (const float*)d_in[5];

    const int T   = in_sizes[1];            // 32768 tokens
    const int D   = in_sizes[3] / VOCAB;    // padded max path depth
    const int nfc = in_sizes[2];            // (V-1)*128

    const int nblocks = (T + TILE - 1) / TILE;   // 2048
    const size_t shmem = (size_t)TILE * ESTRIDE * 4 + (size_t)TILE * D * 8;

    float* pb = (float*)d_ws;                    // [NPART]
    float* pc = pb + NPART;                      // [NPART]
    ushort* fcb = (ushort*)((char*)d_ws + 2 * NPART * sizeof(float));
    const size_t need = 2 * NPART * sizeof(float) + (size_t)nfc * sizeof(ushort);
    float* out = (float*)d_out;

    if (ws_size >= need) {
        hs_pack<<<1024, 256, 0, stream>>>(fc, fcb, nfc);
        hs_main_bf16<<<nblocks, BLOCK, shmem, stream>>>(
            emb, tgt, fcb, pidx, pcode, pmask, T, D, pb, pc);
    } else {
        hs_main_f32<<<nblocks, BLOCK, shmem, stream>>>(
            emb, tgt, fc, pidx, pcode, pmask, T, D, pb, pc);
    }
    hs_finalize<<<1, 256, 0, stream>>>(pb, pc, nblocks, out);
}

// Round 10
// 34.197 us; speedup vs baseline: 1.0380x; 1.0380x over previous
//
#include <hip/hip_runtime.h>

#define TILE    16
#define BLOCK   256
#define EMBED   128
#define VOCAB   50257
#define ESTRIDE 132   // 4*odd floats: spreads rows across bank-groups
#define NPART   2048

// ---------- pre-pass: fc fp32 -> bf16 (round-to-nearest-even) into d_ws ----
__global__ __launch_bounds__(256) void hs_pack(
    const float* __restrict__ fc, ushort* __restrict__ out, int n)
{
    const int stride = gridDim.x * 256 * 8;
    for (int i = (blockIdx.x * 256 + threadIdx.x) * 8; i < n; i += stride) {
        const uint4 a = *(const uint4*)(fc + i);
        const uint4 b = *(const uint4*)(fc + i + 4);
        ushort r[8];
        const uint* u = &a.x;
        #pragma unroll
        for (int j = 0; j < 4; ++j)
            r[j] = (ushort)((u[j] + 0x7FFFu + ((u[j] >> 16) & 1u)) >> 16);
        const uint* v = &b.x;
        #pragma unroll
        for (int j = 0; j < 4; ++j)
            r[4 + j] = (ushort)((v[j] + 0x7FFFu + ((v[j] >> 16) & 1u)) >> 16);
        *(uint4*)(out + i) = *(uint4*)r;
    }
}

// ---------- pipelined main: ONE memory round-trip per wave ----------
// Quad-per-item, d-major (quad g always owns token tk=g). Branchless:
// (1) read all NITER metas from LDS, (2) issue ALL NITER*4 bf16 row loads,
// (3) compute everything. Invalid items load row 0 with weight 0.
template <int NITER>
__global__ __launch_bounds__(BLOCK) void hs_main_pipe(
    const float* __restrict__ emb,        // [T, 128]
    const int*   __restrict__ target,     // [T]
    const ushort* __restrict__ fcb,       // [V-1, 128] bf16
    const int*   __restrict__ path_idx,   // [V, D]
    const float* __restrict__ path_code,  // [V, D]
    const float* __restrict__ path_mask,  // [V, D]
    int T, int D,
    float* __restrict__ partial_b,
    float* __restrict__ partial_c)
{
    constexpr int DP = NITER * 4;                       // padded depth
    extern __shared__ char smem[];
    float* se  = (float*)smem;                          // [TILE*ESTRIDE]
    int2*  sic = (int2*)(smem + TILE * ESTRIDE * 4);    // [TILE*DP], d-major
    __shared__ float sb[BLOCK / 64];
    __shared__ float sc[BLOCK / 64];

    const int tok0 = blockIdx.x * TILE;
    const int ntok = min(TILE, T - tok0);

    // Stage emb tile (zero-fill past ntok).
    const float4* g4 = (const float4*)(emb + (size_t)tok0 * EMBED);
    for (int j = threadIdx.x; j < TILE * (EMBED / 4); j += BLOCK) {
        const int f = j * 4, tk = f >> 7, kk = f & 127;
        float4 v = make_float4(0.f, 0.f, 0.f, 0.f);
        if (tk < ntok) v = g4[j];
        *(float4*)&se[tk * ESTRIDE + kk] = v;
    }
    // Stage path meta d-major, padded to DP: {row, code} or {0,-1}.
    for (int j = threadIdx.x; j < TILE * DP; j += BLOCK) {
        const int tk = j & (TILE - 1), d = j >> 4;
        int2 m = make_int2(0, __float_as_int(-1.0f));
        if (tk < ntok && d < D) {
            const int v = target[tok0 + tk];
            const size_t po = (size_t)v * D + d;
            if (path_mask[po] != 0.f)
                m = make_int2(path_idx[po], __float_as_int(path_code[po]));
        }
        sic[j] = m;
    }
    __syncthreads();

    const int wave = threadIdx.x >> 6;
    const int g    = (threadIdx.x >> 2) & 15;   // quad id == token tk
    const int sub  = threadIdx.x & 3;

    // Quad's token is fixed -> emb fragment into registers once.
    const float4* e4 = (const float4*)&se[g * ESTRIDE];
    float4 ef[8];
    #pragma unroll
    for (int k = 0; k < 4; ++k) {
        ef[2 * k]     = e4[(k * 4 + sub) * 2];
        ef[2 * k + 1] = e4[(k * 4 + sub) * 2 + 1];
    }

    // (1) all metas (independent LDS reads)
    int2 meta[NITER];
    #pragma unroll
    for (int i = 0; i < NITER; ++i)
        meta[i] = sic[wave * 16 + i * 64 + g];

    // (2) issue ALL fc loads before any use (branchless)
    uint4 wv[NITER][4];
    #pragma unroll
    for (int i = 0; i < NITER; ++i) {
        const ushort* wrow = fcb + (size_t)meta[i].x * EMBED;
        #pragma unroll
        for (int k = 0; k < 4; ++k)
            wv[i][k] = *(const uint4*)(wrow + (size_t)((k * 4 + sub) << 3));
    }

    // (3) compute all items
    float accb = 0.f, accc = 0.f;
    #pragma unroll
    for (int i = 0; i < NITER; ++i) {
        const float code = __int_as_float(meta[i].y);
        const float wgt  = code >= 0.f ? 1.f : 0.f;
        const float cd   = fmaxf(code, 0.f);
        float s0 = 0.f, s1 = 0.f;
        #pragma unroll
        for (int k = 0; k < 4; ++k) {
            const uint4  w  = wv[i][k];
            const float4 ea = ef[2 * k];
            const float4 eb = ef[2 * k + 1];
            s0 = fmaf(ea.x, __uint_as_float(w.x << 16),         s0);
            s1 = fmaf(ea.y, __uint_as_float(w.x & 0xFFFF0000u), s1);
            s0 = fmaf(ea.z, __uint_as_float(w.y << 16),         s0);
            s1 = fmaf(ea.w, __uint_as_float(w.y & 0xFFFF0000u), s1);
            s0 = fmaf(eb.x, __uint_as_float(w.z << 16),         s0);
            s1 = fmaf(eb.y, __uint_as_float(w.z & 0xFFFF0000u), s1);
            s0 = fmaf(eb.z, __uint_as_float(w.w << 16),         s0);
            s1 = fmaf(eb.w, __uint_as_float(w.w & 0xFFFF0000u), s1);
        }
        float x = s0 + s1;
        x += __shfl_xor(x, 1);
        x += __shfl_xor(x, 2);
        accb += wgt * (fmaxf(x, 0.f) - x * cd
                       + __logf(1.f + __expf(-fabsf(x))));
        accc += wgt;                          // 4x quad overcount cancels
    }

    #pragma unroll
    for (int o = 32; o > 0; o >>= 1) {
        accb += __shfl_xor(accb, o);
        accc += __shfl_xor(accc, o);
    }
    const int lane = threadIdx.x & 63;
    if (lane == 0) { sb[wave] = accb; sc[wave] = accc; }
    __syncthreads();
    if (threadIdx.x == 0) {
        float b = 0.f, c = 0.f;
        #pragma unroll
        for (int i = 0; i < BLOCK / 64; ++i) { b += sb[i]; c += sc[i]; }
        partial_b[blockIdx.x] = b;
        partial_c[blockIdx.x] = c;
    }
}

// ---------- generic bf16 fallback (R9 loop kernel) for odd D ----------
__global__ __launch_bounds__(BLOCK) void hs_main_bf16(
    const float* __restrict__ emb, const int* __restrict__ target,
    const ushort* __restrict__ fcb, const int* __restrict__ path_idx,
    const float* __restrict__ path_code, const float* __restrict__ path_mask,
    int T, int D, float* __restrict__ partial_b, float* __restrict__ partial_c)
{
    extern __shared__ char smem[];
    float* se  = (float*)smem;
    int2*  sic = (int2*)(smem + TILE * ESTRIDE * 4);
    __shared__ float sb[BLOCK / 64];
    __shared__ float sc[BLOCK / 64];

    const int tok0 = blockIdx.x * TILE;
    const int ntok = min(TILE, T - tok0);

    const float4* g4 = (const float4*)(emb + (size_t)tok0 * EMBED);
    for (int j = threadIdx.x; j < TILE * (EMBED / 4); j += BLOCK) {
        const int f = j * 4, tk = f >> 7, kk = f & 127;
        float4 v = make_float4(0.f, 0.f, 0.f, 0.f);
        if (tk < ntok) v = g4[j];
        *(float4*)&se[tk * ESTRIDE + kk] = v;
    }
    for (int j = threadIdx.x; j < TILE * D; j += BLOCK) {
        const int tk = j & (TILE - 1), d = j >> 4;
        int2 m = make_int2(0, __float_as_int(-1.0f));
        if (tk < ntok) {
            const int v = target[tok0 + tk];
            const size_t po = (size_t)v * D + d;
            if (path_mask[po] != 0.f)
                m = make_int2(path_idx[po], __float_as_int(path_code[po]));
        }
        sic[j] = m;
    }
    __syncthreads();

    const int wave = threadIdx.x >> 6;
    const int g    = (threadIdx.x >> 2) & 15;
    const int sub  = threadIdx.x & 3;
    float accb = 0.f, accc = 0.f;

    const int items = TILE * D;
    for (int it = wave * 16; it < items; it += 64) {
        const int2 m = sic[it + g];
        const float code = __int_as_float(m.y);
        if (code >= 0.f) {
            const ushort* wrow = fcb + (size_t)m.x * EMBED;
            const float4* e4   = (const float4*)&se[g * ESTRIDE];
            float s0 = 0.f, s1 = 0.f;
            #pragma unroll
            for (int k = 0; k < 4; ++k) {
                const int c8 = k * 4 + sub;
                const uint4  w  = *(const uint4*)(wrow + (c8 << 3));
                const float4 ea = e4[c8 * 2];
                const float4 eb = e4[c8 * 2 + 1];
                s0 = fmaf(ea.x, __uint_as_float(w.x << 16),         s0);
                s1 = fmaf(ea.y, __uint_as_float(w.x & 0xFFFF0000u), s1);
                s0 = fmaf(ea.z, __uint_as_float(w.y << 16),         s0);
                s1 = fmaf(ea.w, __uint_as_float(w.y & 0xFFFF0000u), s1);
                s0 = fmaf(eb.x, __uint_as_float(w.z << 16),         s0);
                s1 = fmaf(eb.y, __uint_as_float(w.z & 0xFFFF0000u), s1);
                s0 = fmaf(eb.z, __uint_as_float(w.w << 16),         s0);
                s1 = fmaf(eb.w, __uint_as_float(w.w & 0xFFFF0000u), s1);
            }
            float x = s0 + s1;
            x += __shfl_xor(x, 1);
            x += __shfl_xor(x, 2);
            accb += fmaxf(x, 0.f) - x * code + __logf(1.f + __expf(-fabsf(x)));
            accc += 1.f;
        }
    }
    #pragma unroll
    for (int o = 32; o > 0; o >>= 1) {
        accb += __shfl_xor(accb, o);
        accc += __shfl_xor(accc, o);
    }
    const int lane = threadIdx.x & 63;
    if (lane == 0) { sb[wave] = accb; sc[wave] = accc; }
    __syncthreads();
    if (threadIdx.x == 0) {
        float b = 0.f, c = 0.f;
        #pragma unroll
        for (int i = 0; i < BLOCK / 64; ++i) { b += sb[i]; c += sc[i]; }
        partial_b[blockIdx.x] = b;
        partial_c[blockIdx.x] = c;
    }
}

// ---------- fp32 fallback if ws too small ----------
__global__ __launch_bounds__(BLOCK) void hs_main_f32(
    const float* __restrict__ emb, const int* __restrict__ target,
    const float* __restrict__ fc,  const int* __restrict__ path_idx,
    const float* __restrict__ path_code, const float* __restrict__ path_mask,
    int T, int D, float* __restrict__ partial_b, float* __restrict__ partial_c)
{
    extern __shared__ char smem[];
    float* se  = (float*)smem;
    int2*  sic = (int2*)(smem + TILE * ESTRIDE * 4);
    __shared__ float sb[BLOCK / 64];
    __shared__ float sc[BLOCK / 64];

    const int tok0 = blockIdx.x * TILE;
    const int ntok = min(TILE, T - tok0);

    const float4* g4 = (const float4*)(emb + (size_t)tok0 * EMBED);
    for (int j = threadIdx.x; j < TILE * (EMBED / 4); j += BLOCK) {
        const int f = j * 4, tk = f >> 7, kk = f & 127;
        float4 v = make_float4(0.f, 0.f, 0.f, 0.f);
        if (tk < ntok) v = g4[j];
        *(float4*)&se[tk * ESTRIDE + kk] = v;
    }
    for (int j = threadIdx.x; j < TILE * D; j += BLOCK) {
        const int tk = j & (TILE - 1), d = j >> 4;
        int2 m = make_int2(0, __float_as_int(-1.0f));
        if (tk < ntok) {
            const int v = target[tok0 + tk];
            const size_t po = (size_t)v * D + d;
            if (path_mask[po] != 0.f)
                m = make_int2(path_idx[po], __float_as_int(path_code[po]));
        }
        sic[j] = m;
    }
    __syncthreads();

    const int wave = threadIdx.x >> 6;
    const int g    = (threadIdx.x >> 2) & 15;
    const int sub  = threadIdx.x & 3;
    float accb = 0.f, accc = 0.f;

    const int items = TILE * D;
    for (int it = wave * 16; it < items; it += 64) {
        const int2 m = sic[it + g];
        const float code = __int_as_float(m.y);
        if (code >= 0.f) {
            const float4* w4 = (const float4*)(fc + (size_t)m.x * EMBED);
            const float4* e4 = (const float4*)&se[g * ESTRIDE];
            float s0 = 0.f, s1 = 0.f, s2 = 0.f, s3 = 0.f;
            #pragma unroll
            for (int k = 0; k < 8; ++k) {
                const float4 w  = w4[k * 4 + sub];
                const float4 ev = e4[k * 4 + sub];
                s0 = fmaf(ev.x, w.x, s0); s1 = fmaf(ev.y, w.y, s1);
                s2 = fmaf(ev.z, w.z, s2); s3 = fmaf(ev.w, w.w, s3);
            }
            float x = (s0 + s1) + (s2 + s3);
            x += __shfl_xor(x, 1); x += __shfl_xor(x, 2);
            accb += fmaxf(x, 0.f) - x * code + __logf(1.f + __expf(-fabsf(x)));
            accc += 1.f;
        }
    }
    #pragma unroll
    for (int o = 32; o > 0; o >>= 1) {
        accb += __shfl_xor(accb, o);
        accc += __shfl_xor(accc, o);
    }
    const int lane = threadIdx.x & 63;
    if (lane == 0) { sb[wave] = accb; sc[wave] = accc; }
    __syncthreads();
    if (threadIdx.x == 0) {
        float b = 0.f, c = 0.f;
        #pragma unroll
        for (int i = 0; i < BLOCK / 64; ++i) { b += sb[i]; c += sc[i]; }
        partial_b[blockIdx.x] = b;
        partial_c[blockIdx.x] = c;
    }
}

// ---------- deterministic finalize ----------
__global__ __launch_bounds__(256) void hs_finalize(
    const float* __restrict__ pb, const float* __restrict__ pc,
    int n, float* __restrict__ out)
{
    __shared__ double rb[256];
    __shared__ double rc[256];
    double sbv = 0.0, scv = 0.0;
    for (int i = threadIdx.x; i < n; i += 256) {
        sbv += (double)pb[i];
        scv += (double)pc[i];
    }
    rb[threadIdx.x] = sbv; rc[threadIdx.x] = scv;
    __syncthreads();
    for (int s = 128; s > 0; s >>= 1) {
        if (threadIdx.x < s) {
            rb[threadIdx.x] += rb[threadIdx.x + s];
            rc[threadIdx.x] += rc[threadIdx.x + s];
        }
        __syncthreads();
    }
    if (threadIdx.x == 0) out[0] = (float)(rb[0] / rc[0]);
}

extern "C" void kernel_launch(void* const* d_in, const int* in_sizes, int n_in,
                              void* d_out, int out_size, void* d_ws, size_t ws_size,
                              hipStream_t stream) {
    const float* emb   = (const float*)d_in[0];
    const int*   tgt   = (const int*)  d_in[1];
    const float* fc    = (const float*)d_in[2];
    const int*   pidx  = (const int*)  d_in[3];
    const float* pcode = (const float*)d_in[4];
    const float* pmask = (const float*)d_in[5];

    const int T   = in_sizes[1];            // 32768 tokens
    const int D   = in_sizes[3] / VOCAB;    // padded max path depth
    const int nfc = in_sizes[2];            // (V-1)*128

    const int nblocks = (T + TILE - 1) / TILE;   // 2048
    const int niter   = (D + 3) / 4;
    const int DP      = niter * 4;
    const size_t shmem_pipe = (size_t)TILE * ESTRIDE * 4 + (size_t)TILE * DP * 8;
    const size_t shmem_loop = (size_t)TILE * ESTRIDE * 4 + (size_t)TILE * D * 8;

    float* pb = (float*)d_ws;                    // [NPART]
    float* pc = pb + NPART;                      // [NPART]
    ushort* fcb = (ushort*)((char*)d_ws + 2 * NPART * sizeof(float));
    const size_t need = 2 * NPART * sizeof(float) + (size_t)nfc * sizeof(ushort);
    float* out = (float*)d_out;

    if (ws_size >= need) {
        hs_pack<<<1024, 256, 0, stream>>>(fc, fcb, nfc);
        switch (niter) {
        case 1: hs_main_pipe<1><<<nblocks, BLOCK, shmem_pipe, stream>>>(
                    emb, tgt, fcb, pidx, pcode, pmask, T, D, pb, pc); break;
        case 2: hs_main_pipe<2><<<nblocks, BLOCK, shmem_pipe, stream>>>(
                    emb, tgt, fcb, pidx, pcode, pmask, T, D, pb, pc); break;
        case 3: hs_main_pipe<3><<<nblocks, BLOCK, shmem_pipe, stream>>>(
                    emb, tgt, fcb, pidx, pcode, pmask, T, D, pb, pc); break;
        case 4: hs_main_pipe<4><<<nblocks, BLOCK, shmem_pipe, stream>>>(
                    emb, tgt, fcb, pidx, pcode, pmask, T, D, pb, pc); break;
        case 5: hs_main_pipe<5><<<nblocks, BLOCK, shmem_pipe, stream>>>(
                    emb, tgt, fcb, pidx, pcode, pmask, T, D, pb, pc); break;
        case 6: hs_main_pipe<6><<<nblocks, BLOCK, shmem_pipe, stream>>>(
                    emb, tgt, fcb, pidx, pcode, pmask, T, D, pb, pc); break;
        case 7: hs_main_pipe<7><<<nblocks, BLOCK, shmem_pipe, stream>>>(
                    emb, tgt, fcb, pidx, pcode, pmask, T, D, pb, pc); break;
        case 8: hs_main_pipe<8><<<nblocks, BLOCK, shmem_pipe, stream>>>(
                    emb, tgt, fcb, pidx, pcode, pmask, T, D, pb, pc); break;
        default:
            hs_main_bf16<<<nblocks, BLOCK, shmem_loop, stream>>>(
                emb, tgt, fcb, pidx, pcode, pmask, T, D, pb, pc); break;
        }
    } else {
        hs_main_f32<<<nblocks, BLOCK, shmem_loop, stream>>>(
            emb, tgt, fc, pidx, pcode, pmask, T, D, pb, pc);
    }
    hs_finalize<<<1, 256, 0, stream>>>(pb, pc, nblocks, out);
}